// Round 3
// baseline (84.462 us; speedup 1.0000x reference)
//
#include <hip/hip_runtime.h>
#include <cstdint>

#define NN 4096
#define FF 512

typedef short bf16x8 __attribute__((ext_vector_type(8)));
typedef float f32x16 __attribute__((ext_vector_type(16)));

__device__ __forceinline__ uint16_t f2bf(float f) {
    uint32_t u = __builtin_bit_cast(uint32_t, f);
    u += 0x7FFFu + ((u >> 16) & 1u);   // round-to-nearest-even
    return (uint16_t)(u >> 16);
}

// ---------------------------------------------------------------------------
// k_prep: A_bf[i][j] = bf16( d_i * (adj[i][j] + (i==j)) ), d_i = rsqrt(1 + rowsum)
// ---------------------------------------------------------------------------
__global__ __launch_bounds__(256) void k_prep(const float* __restrict__ adj,
                                              float* __restrict__ d,
                                              uint16_t* __restrict__ Abf) {
    const int row  = blockIdx.x * 4 + (threadIdx.x >> 6);
    const int lane = threadIdx.x & 63;
    const float4* p = (const float4*)(adj + (size_t)row * NN);
    float4 v[16];
    float s = 0.f;
#pragma unroll
    for (int i = 0; i < 16; ++i) {
        v[i] = p[lane + i * 64];
        s += (v[i].x + v[i].y) + (v[i].z + v[i].w);
    }
#pragma unroll
    for (int off = 1; off < 64; off <<= 1) s += __shfl_xor(s, off);
    const float di = rsqrtf(s + 1.0f);
    if (lane == 0) d[row] = di;
    uint16_t* outp = Abf + (size_t)row * NN;
#pragma unroll
    for (int i = 0; i < 16; ++i) {
        const int cb = (lane + i * 64) * 4;
        float a0 = v[i].x * di, a1 = v[i].y * di, a2 = v[i].z * di, a3 = v[i].w * di;
        if (cb + 0 == row) a0 += di;
        if (cb + 1 == row) a1 += di;
        if (cb + 2 == row) a2 += di;
        if (cb + 3 == row) a3 += di;
        ushort4 o;
        o.x = f2bf(a0); o.y = f2bf(a1); o.z = f2bf(a2); o.w = f2bf(a3);
        *(ushort4*)(outp + cb) = o;
    }
}

// ---------------------------------------------------------------------------
// k_xt: yT[n][k] = bf16(d[k] * x[k][n])
// ---------------------------------------------------------------------------
__global__ __launch_bounds__(256) void k_xt(const float* __restrict__ x,
                                            const float* __restrict__ d,
                                            uint16_t* __restrict__ yT) {
    __shared__ uint16_t t[64][72];
    const int k0 = blockIdx.x * 64;
    const int n0 = blockIdx.y * 64;
    const int tid = threadIdx.x;
    const int r   = tid >> 4;
    const int c4  = tid & 15;
#pragma unroll
    for (int pass = 0; pass < 4; ++pass) {
        const int row = pass * 16 + r;
        float4 v = *(const float4*)(x + (size_t)(k0 + row) * FF + n0 + c4 * 4);
        const float dk = d[k0 + row];
        t[c4 * 4 + 0][row] = f2bf(v.x * dk);
        t[c4 * 4 + 1][row] = f2bf(v.y * dk);
        t[c4 * 4 + 2][row] = f2bf(v.z * dk);
        t[c4 * 4 + 3][row] = f2bf(v.w * dk);
    }
    __syncthreads();
#pragma unroll
    for (int pass = 0; pass < 2; ++pass) {
        const int cid = pass * 256 + tid;
        const int n  = cid >> 3;
        const int ch = cid & 7;
        *(uint4*)(yT + (size_t)(n0 + n) * NN + k0 + ch * 8) = *(const uint4*)&t[n][ch * 8];
    }
}

// ---------------------------------------------------------------------------
// k_wc: W f32 -> bf16
// ---------------------------------------------------------------------------
__global__ __launch_bounds__(256) void k_wc(const float* __restrict__ W,
                                            uint16_t* __restrict__ Wbf) {
    const size_t t4 = (size_t)blockIdx.x * 256 + threadIdx.x;
    float4 v = *(const float4*)(W + t4 * 4);
    ushort4 o;
    o.x = f2bf(v.x); o.y = f2bf(v.y); o.z = f2bf(v.z); o.w = f2bf(v.w);
    *(ushort4*)(Wbf + t4 * 4) = o;
}

// ---------------------------------------------------------------------------
// k_cvt: h32 f32 -> hbf bf16
// ---------------------------------------------------------------------------
__global__ __launch_bounds__(256) void k_cvt(const float* __restrict__ h32,
                                             uint16_t* __restrict__ hbf) {
    const size_t t4 = (size_t)blockIdx.x * 256 + threadIdx.x;
    float4 v = *(const float4*)(h32 + t4 * 4);
    ushort4 o;
    o.x = f2bf(v.x); o.y = f2bf(v.y); o.z = f2bf(v.z); o.w = f2bf(v.w);
    *(ushort4*)(hbf + t4 * 4) = o;
}

// ---------------------------------------------------------------------------
// k_gemm: C[4096][512] += A[4096][K] * Bt[512][K]^T   (bf16 operands)
// BM=128, BN=64*NF, BK=64. 4 waves (2x2), per-wave 64 x 32*NF of 32x32x16 frags.
// 32 FLOP per LDS byte (vs 16 with 16x16 frags). Double-buffer LDS,
// counted vmcnt keeps the next tile's loads in flight across barriers.
// MODE 0: atomicAdd f32 partial (split-K).  MODE 1: f32 + bias final store.
// ---------------------------------------------------------------------------
template <int K, int SPLITK, int NF, int MODE>
__global__ __launch_bounds__(256, 1) void k_gemm(const uint16_t* __restrict__ A,
                                                 const uint16_t* __restrict__ Bt,
                                                 const float* __restrict__ bias,
                                                 float* __restrict__ outf) {
    constexpr int KS = K / SPLITK;   // K handled per block
    constexpr int NT = KS / 64;      // ktiles
    constexpr int BN = 64 * NF;
    constexpr int NTIL = 512 / BN;
    __shared__ uint16_t As[2][128 * 64];
    __shared__ uint16_t Bs[2][BN * 64];

    // id = j*8 + xcd : same m-stripe stays on one XCD's L2
    const int id  = blockIdx.x;
    const int xcd = id & 7;
    const int j   = id >> 3;
    const int mt  = ((j / (NTIL * SPLITK)) << 3) | xcd;
    const int rem = j % (NTIL * SPLITK);
    const int nt  = rem / SPLITK;
    const int ks  = rem % SPLITK;
    const int m0 = mt * 128;
    const int n0 = nt * BN;
    const int k0 = ks * KS;

    const int tid  = threadIdx.x;
    const int w    = tid >> 6;
    const int lane = tid & 63;
    const int wm = w >> 1, wn = w & 1;

    f32x16 acc[2][NF] = {};

    auto STAGE = [&](int t, int buf) {
        const int ktb = k0 + t * 64;
#pragma unroll
        for (int i = 0; i < 4; ++i) {          // A tile: 16KB
            const int boff = i * 4096 + tid * 16;
            const int row  = boff >> 7;
            const int q    = (boff >> 4) & 7;
            const int c    = q ^ (row & 7);    // inverse-swizzled global source
            const uint16_t* src = A + (size_t)(m0 + row) * K + ktb + c * 8;
            __builtin_amdgcn_global_load_lds(
                (const __attribute__((address_space(1))) void*)src,
                (__attribute__((address_space(3))) void*)&As[buf][i * 2048 + w * 512],
                16, 0, 0);
        }
#pragma unroll
        for (int i = 0; i < NF * 2; ++i) {     // B tile: NF*8KB
            const int boff = i * 4096 + tid * 16;
            const int row  = boff >> 7;
            const int q    = (boff >> 4) & 7;
            const int c    = q ^ (row & 7);
            const uint16_t* src = Bt + (size_t)(n0 + row) * K + ktb + c * 8;
            __builtin_amdgcn_global_load_lds(
                (const __attribute__((address_space(1))) void*)src,
                (__attribute__((address_space(3))) void*)&Bs[buf][i * 2048 + w * 512],
                16, 0, 0);
        }
    };

    auto COMPUTE = [&](int buf) {
#pragma unroll
        for (int ksl = 0; ksl < 4; ++ksl) {    // 4 k-slices of 16
            const int cl = ksl * 2 + (lane >> 5);
            bf16x8 af[2], bfr[NF];
#pragma unroll
            for (int mf = 0; mf < 2; ++mf) {
                const int r = wm * 64 + mf * 32 + (lane & 31);
                af[mf] = *(const bf16x8*)&As[buf][r * 64 + ((cl ^ (r & 7)) << 3)];
            }
#pragma unroll
            for (int nf = 0; nf < NF; ++nf) {
                const int r = wn * (32 * NF) + nf * 32 + (lane & 31);
                bfr[nf] = *(const bf16x8*)&Bs[buf][r * 64 + ((cl ^ (r & 7)) << 3)];
            }
#pragma unroll
            for (int mf = 0; mf < 2; ++mf)
#pragma unroll
                for (int nf = 0; nf < NF; ++nf)
                    acc[mf][nf] = __builtin_amdgcn_mfma_f32_32x32x16_bf16(
                        af[mf], bfr[nf], acc[mf][nf], 0, 0, 0);
        }
    };

    STAGE(0, 0);
    for (int t = 0; t < NT - 1; ++t) {
        STAGE(t + 1, (t + 1) & 1);
        if constexpr (NF == 2) asm volatile("s_waitcnt vmcnt(8)" ::: "memory");
        else                   asm volatile("s_waitcnt vmcnt(6)" ::: "memory");
        __builtin_amdgcn_s_barrier();
        COMPUTE(t & 1);
        __builtin_amdgcn_s_barrier();
    }
    asm volatile("s_waitcnt vmcnt(0)" ::: "memory");
    __builtin_amdgcn_s_barrier();
    COMPUTE((NT - 1) & 1);

    // epilogue: C/D 32x32 layout col=lane&31, row=(reg&3)+8*(reg>>2)+4*(lane>>5)
#pragma unroll
    for (int mf = 0; mf < 2; ++mf) {
#pragma unroll
        for (int nf = 0; nf < NF; ++nf) {
            const int gcol = n0 + wn * (32 * NF) + nf * 32 + (lane & 31);
            const int rb   = m0 + wm * 64 + mf * 32 + ((lane >> 5) << 2);
            float bv = 0.f;
            if constexpr (MODE == 1) bv = bias[gcol];
#pragma unroll
            for (int r = 0; r < 16; ++r) {
                const int grow = rb + (r & 3) + ((r >> 2) << 3);
                const size_t idx = (size_t)grow * FF + gcol;
                if constexpr (MODE == 0) {
                    atomicAdd(&outf[idx], acc[mf][nf][r]);
                } else {
                    outf[idx] = acc[mf][nf][r] + bv;
                }
            }
        }
    }
}

// ---------------------------------------------------------------------------
extern "C" void kernel_launch(void* const* d_in, const int* in_sizes, int n_in,
                              void* d_out, int out_size, void* d_ws, size_t ws_size,
                              hipStream_t stream) {
    const float* x   = (const float*)d_in[0];   // [4096][512]
    const float* adj = (const float*)d_in[1];   // [4096][4096]
    const float* W   = (const float*)d_in[2];   // [512][512]
    const float* b   = (const float*)d_in[3];   // [512]
    float* out = (float*)d_out;                 // [4096][512] f32

    char* ws = (char*)d_ws;
    float*    d_   = (float*)ws;                                  // 16 KB (pad 64K)
    uint16_t* Abf  = (uint16_t*)(ws + 65536);                     // 32 MB
    uint16_t* yT   = Abf + (size_t)NN * NN;                       // 4 MB
    uint16_t* hbf  = yT  + (size_t)FF * NN;                       // 4 MB
    uint16_t* Wbf  = hbf + (size_t)NN * FF;                       // 0.5 MB
    float*    h32  = (float*)(Wbf + (size_t)FF * FF);             // 8 MB f32

    hipMemsetAsync(h32, 0, (size_t)NN * FF * sizeof(float), stream);
    k_prep<<<NN / 4, 256, 0, stream>>>(adj, d_, Abf);
    k_xt<<<dim3(NN / 64, FF / 64), 256, 0, stream>>>(x, d_, yT);
    k_wc<<<FF * FF / 4 / 256, 256, 0, stream>>>(W, Wbf);
    // GEMM1: h32 += (split-K halves of) Abf @ yT^T   [256 blocks]
    k_gemm<NN, 2, 2, 0><<<256, 256, 0, stream>>>(Abf, yT, nullptr, h32);
    k_cvt<<<NN * FF / 4 / 256, 256, 0, stream>>>(h32, hbf);
    // GEMM2: out = hbf @ Wbf^T + b                    [256 blocks]
    k_gemm<FF, 1, 1, 1><<<256, 256, 0, stream>>>(hbf, Wbf, b, out);
}